// Round 1
// 589.886 us; speedup vs baseline: 1.0465x; 1.0465x over previous
//
#include <hip/hip_runtime.h>

#define HIDDEN 2048
#define HEAD_DIM 128
#define NUM_KV 8
#define BATCH 32
#define MAX_PAGES 128
#define PAGE 16
#define QKV_COLS 4096          // 2048 q | 1024 k | 1024 v
#define KSPLIT1 32
#define KCH1 (HIDDEN / KSPLIT1)   // 64
#define CSPLIT 8
#define PAGES_PER_SPLIT (MAX_PAGES / CSPLIT)  // 16
#define KSPLIT2 32
#define KCH2 (HIDDEN / KSPLIT2)   // 64

// ws layout (float offsets). Regions reused across sequential phases.
#define WS_QKVP 0                 // 32*32*4096 = 4194304
#define WS_QBUF 4194304           // 65536 (q post norm+rope, f32)
#define WS_AOUT 4259840           // 65536 (attn output, f32)
#define WS_PACC 0                 // 32*8*8*256 = 524288 (reuses QKVP region)
#define WS_PML  524288            // 32*8*8*4 = 8192
#define WS_OUTP 0                 // 32*65536 = 2097152 (reuses again)
// high-water: 4325376 floats = 17.3 MB

// --- kernel 1: QKV projection partials. grid (32 colblocks, KSPLIT1), 128 thr ---
// 8-deep weight prefetch: 8 coalesced loads in flight during each 256-FMA stage.
__global__ __launch_bounds__(128) void qkv_partial_kernel(
    const float* __restrict__ x, const float* __restrict__ wq,
    const float* __restrict__ wk, const float* __restrict__ wv,
    float* __restrict__ part) {
  int n = blockIdx.x * 128 + threadIdx.x;   // 0..4095
  int kz = blockIdx.y;
  int k0 = kz * KCH1;
  const float* W; int ldw, col;             // block-uniform branch (128-col blocks)
  if (n < 2048)      { W = wq; ldw = 2048; col = n; }
  else if (n < 3072) { W = wk; ldw = 1024; col = n - 2048; }
  else               { W = wv; ldw = 1024; col = n - 3072; }
  const float* Wp = W + (size_t)k0 * ldw + col;
  float acc[BATCH];
#pragma unroll
  for (int b = 0; b < BATCH; ++b) acc[b] = 0.f;
  float wa[8], wb[8];
#pragma unroll
  for (int j = 0; j < 8; ++j) wa[j] = Wp[(size_t)j * ldw];
#pragma unroll
  for (int kk = 0; kk < KCH1; kk += 16) {
#pragma unroll
    for (int j = 0; j < 8; ++j) wb[j] = Wp[(size_t)(kk + 8 + j) * ldw];
#pragma unroll
    for (int j = 0; j < 8; ++j) {
#pragma unroll
      for (int b = 0; b < BATCH; ++b)
        acc[b] = fmaf(x[b * HIDDEN + k0 + kk + j], wa[j], acc[b]);  // x uniform -> s_load
    }
    if (kk + 16 < KCH1) {
#pragma unroll
      for (int j = 0; j < 8; ++j) wa[j] = Wp[(size_t)(kk + 16 + j) * ldw];
    }
#pragma unroll
    for (int j = 0; j < 8; ++j) {
#pragma unroll
      for (int b = 0; b < BATCH; ++b)
        acc[b] = fmaf(x[b * HIDDEN + k0 + kk + 8 + j], wb[j], acc[b]);
    }
  }
#pragma unroll
  for (int b = 0; b < BATCH; ++b)
    part[((size_t)kz * BATCH + b) * QKV_COLS + n] = acc[b];
}

// --- kernel 2: reduce partials, rmsnorm + rope, emit q(ws f32), k,v (d_out f32) ---
// grid (32 batch, 32 slots: 16 q heads, 8 k heads, 8 v heads), 128 thr
__global__ __launch_bounds__(128) void qkv_finish_kernel(
    const float* __restrict__ part, const float* __restrict__ cosb,
    const float* __restrict__ sinb, const float* __restrict__ qnw,
    const float* __restrict__ knw, float* __restrict__ qbuf,
    float* __restrict__ outk, float* __restrict__ outv) {
  int b = blockIdx.x;
  int s = blockIdx.y;
  int d = threadIdx.x;
  int col;
  if (s < 16)      col = s * 128 + d;
  else if (s < 24) col = 2048 + (s - 16) * 128 + d;
  else             col = 3072 + (s - 24) * 128 + d;
  float val = 0.f;
#pragma unroll
  for (int z = 0; z < KSPLIT1; ++z)
    val += part[((size_t)z * BATCH + b) * QKV_COLS + col];
  if (s >= 24) {  // v: raw projection, straight to output (block-uniform branch)
    outv[b * 1024 + (s - 24) * 128 + d] = val;
    return;
  }
  __shared__ float red[128];
  __shared__ float xs[128];
  red[d] = val * val;
  __syncthreads();
#pragma unroll
  for (int st = 64; st > 0; st >>= 1) {
    if (d < st) red[d] += red[d + st];
    __syncthreads();
  }
  float var = red[0] * (1.f / 128.f);
  float inv = rsqrtf(var + 1e-6f);
  const float* nw = (s < 16) ? qnw : knw;
  float xn = val * inv * nw[d];
  xs[d] = xn;
  __syncthreads();
  float c  = cosb[b * 128 + d];
  float sn = sinb[b * 128 + d];
  float rot = (d < 64) ? -xs[d + 64] : xs[d - 64];
  float o = xn * c + rot * sn;
  if (s < 16) qbuf[b * 2048 + s * 128 + d] = o;
  else        outk[b * 1024 + (s - 16) * 128 + d] = o;
}

// --- kernel 3: flash-decode attention, barrier-free main loop. ---
// grid (32, 8 kvh, 8 splits), 256 thr. Thread (pos,dp) keeps a private
// online-softmax state over its own token positions (one token per page);
// cross-pos merge happens ONCE per split via LDS. No per-page barriers,
// no per-page vmcnt(0) drain -> pages pipeline; K/V prefetched 1 page ahead.
__global__ __launch_bounds__(256) void attn_kernel(
    const float* __restrict__ qbuf, const float* __restrict__ kc,
    const float* __restrict__ vc, const int* __restrict__ btab,
    const int* __restrict__ clen, float* __restrict__ pacc,
    float* __restrict__ pml) {
  int b = blockIdx.x, g = blockIdx.y, sp = blockIdx.z;
  int tid = threadIdx.x;
  const float NEG_INF = -__builtin_huge_valf();
  int ctx = clen[b];
  int npages = (ctx + PAGE - 1) >> 4;
  int p0 = sp * PAGES_PER_SPLIT;
  int p1 = min(p0 + PAGES_PER_SPLIT, npages);

  int pos = tid >> 4, dp = tid & 15;
  float ql0[8], ql1[8];
  {
    const float4* q0 = (const float4*)(qbuf + b * 2048 + (g * 2 + 0) * 128 + dp * 8);
    const float4* q1 = (const float4*)(qbuf + b * 2048 + (g * 2 + 1) * 128 + dp * 8);
    float4 a = q0[0], c = q0[1];
    ql0[0]=a.x; ql0[1]=a.y; ql0[2]=a.z; ql0[3]=a.w;
    ql0[4]=c.x; ql0[5]=c.y; ql0[6]=c.z; ql0[7]=c.w;
    a = q1[0]; c = q1[1];
    ql1[0]=a.x; ql1[1]=a.y; ql1[2]=a.z; ql1[3]=a.w;
    ql1[4]=c.x; ql1[5]=c.y; ql1[6]=c.z; ql1[7]=c.w;
  }
  float acc0[8], acc1[8];
#pragma unroll
  for (int j = 0; j < 8; ++j) { acc0[j] = 0.f; acc1[j] = 0.f; }
  float m0 = NEG_INF, m1 = NEG_INF, l0 = 0.f, l1 = 0.f;
  const float scale = 0.08838834764831845f;

  float4 ck0, ck1, cv0, cv1;
  if (p0 < p1) {
    int page = btab[b * MAX_PAGES + p0];
    size_t base = ((size_t)(page * PAGE + pos) * NUM_KV + g) * HEAD_DIM + dp * 8;
    const float4* kp = (const float4*)(kc + base);
    const float4* vp = (const float4*)(vc + base);
    ck0 = kp[0]; ck1 = kp[1]; cv0 = vp[0]; cv1 = vp[1];
  }
  for (int p = p0; p < p1; ++p) {
    float4 nk0, nk1, nv0, nv1;
    if (p + 1 < p1) {              // prefetch next page (block-uniform branch)
      int page = btab[b * MAX_PAGES + p + 1];
      size_t base = ((size_t)(page * PAGE + pos) * NUM_KV + g) * HEAD_DIM + dp * 8;
      const float4* kp = (const float4*)(kc + base);
      const float4* vp = (const float4*)(vc + base);
      nk0 = kp[0]; nk1 = kp[1]; nv0 = vp[0]; nv1 = vp[1];
    }
    float s0 = 0.f, s1 = 0.f;
    s0 = fmaf(ck0.x, ql0[0], s0); s1 = fmaf(ck0.x, ql1[0], s1);
    s0 = fmaf(ck0.y, ql0[1], s0); s1 = fmaf(ck0.y, ql1[1], s1);
    s0 = fmaf(ck0.z, ql0[2], s0); s1 = fmaf(ck0.z, ql1[2], s1);
    s0 = fmaf(ck0.w, ql0[3], s0); s1 = fmaf(ck0.w, ql1[3], s1);
    s0 = fmaf(ck1.x, ql0[4], s0); s1 = fmaf(ck1.x, ql1[4], s1);
    s0 = fmaf(ck1.y, ql0[5], s0); s1 = fmaf(ck1.y, ql1[5], s1);
    s0 = fmaf(ck1.z, ql0[6], s0); s1 = fmaf(ck1.z, ql1[6], s1);
    s0 = fmaf(ck1.w, ql0[7], s0); s1 = fmaf(ck1.w, ql1[7], s1);
#pragma unroll
    for (int off = 1; off < 16; off <<= 1) {
      s0 += __shfl_xor(s0, off);
      s1 += __shfl_xor(s1, off);
    }
    bool valid = (p * PAGE + pos) < ctx;
    if (valid) {
      float t0 = s0 * scale;
      float mn = fmaxf(m0, t0);
      float a  = __expf(m0 - mn);      // m0=-inf first time -> 0
      float w  = __expf(t0 - mn);
      l0 = fmaf(l0, a, w); m0 = mn;
      acc0[0] = fmaf(acc0[0], a, w * cv0.x);
      acc0[1] = fmaf(acc0[1], a, w * cv0.y);
      acc0[2] = fmaf(acc0[2], a, w * cv0.z);
      acc0[3] = fmaf(acc0[3], a, w * cv0.w);
      acc0[4] = fmaf(acc0[4], a, w * cv1.x);
      acc0[5] = fmaf(acc0[5], a, w * cv1.y);
      acc0[6] = fmaf(acc0[6], a, w * cv1.z);
      acc0[7] = fmaf(acc0[7], a, w * cv1.w);
      float t1 = s1 * scale;
      float mn1 = fmaxf(m1, t1);
      float a1  = __expf(m1 - mn1);
      float w1  = __expf(t1 - mn1);
      l1 = fmaf(l1, a1, w1); m1 = mn1;
      acc1[0] = fmaf(acc1[0], a1, w1 * cv0.x);
      acc1[1] = fmaf(acc1[1], a1, w1 * cv0.y);
      acc1[2] = fmaf(acc1[2], a1, w1 * cv0.z);
      acc1[3] = fmaf(acc1[3], a1, w1 * cv0.w);
      acc1[4] = fmaf(acc1[4], a1, w1 * cv1.x);
      acc1[5] = fmaf(acc1[5], a1, w1 * cv1.y);
      acc1[6] = fmaf(acc1[6], a1, w1 * cv1.z);
      acc1[7] = fmaf(acc1[7], a1, w1 * cv1.w);
    }
    ck0 = nk0; ck1 = nk1; cv0 = nv0; cv1 = nv1;
  }

  // --- once-per-split merge across the 16 pos groups ---
  __shared__ float m_s[2][16], l_s[2][16];
  __shared__ float acc_s[2][16][128];
  if (dp == 0) {   // m,l identical across the 16-lane group (post-shfl)
    m_s[0][pos] = m0; m_s[1][pos] = m1;
    l_s[0][pos] = l0; l_s[1][pos] = l1;
  }
#pragma unroll
  for (int j = 0; j < 8; ++j) {
    acc_s[0][pos][dp * 8 + j] = acc0[j];
    acc_s[1][pos][dp * 8 + j] = acc1[j];
  }
  __syncthreads();
  int r2 = tid >> 7, d2 = tid & 127;
  float M = NEG_INF;
#pragma unroll
  for (int q = 0; q < 16; ++q) M = fmaxf(M, m_s[r2][q]);
  float accT = 0.f, lT = 0.f;
  if (M != NEG_INF) {              // empty split -> zeros, M=-inf (combine handles)
#pragma unroll
    for (int q = 0; q < 16; ++q) {
      float w = __expf(m_s[r2][q] - M);   // m_s=-inf -> w=0
      accT = fmaf(w, acc_s[r2][q][d2], accT);
      lT   = fmaf(w, l_s[r2][q], lT);
    }
  }
  size_t pidx = ((size_t)b * NUM_KV + g) * CSPLIT + sp;
  pacc[pidx * 256 + tid] = accT;
  if (d2 == 0) {
    pml[pidx * 4 + r2 * 2 + 0] = M;
    pml[pidx * 4 + r2 * 2 + 1] = lT;
  }
}

// --- kernel 4: merge splits. grid (32, 8), 256 thr ---
__global__ __launch_bounds__(256) void attn_combine_kernel(
    const float* __restrict__ pacc, const float* __restrict__ pml,
    float* __restrict__ attn_out) {
  int b = blockIdx.x, g = blockIdx.y, tid = threadIdx.x;
  int r = tid >> 7, d = tid & 127;
  size_t base = ((size_t)b * NUM_KV + g) * CSPLIT;
  float M = -__builtin_huge_valf();
#pragma unroll
  for (int s = 0; s < CSPLIT; ++s)
    M = fmaxf(M, pml[(base + s) * 4 + r * 2]);
  float accT = 0.f, lT = 0.f;
#pragma unroll
  for (int s = 0; s < CSPLIT; ++s) {
    float ms = pml[(base + s) * 4 + r * 2];
    float ls = pml[(base + s) * 4 + r * 2 + 1];
    float w = __expf(ms - M);          // empty split: exp(-inf)=0
    accT = fmaf(w, pacc[(base + s) * 256 + tid], accT);
    lT = fmaf(w, ls, lT);
  }
  attn_out[b * 2048 + (g * 2 + r) * 128 + d] = accT / lT;   // lT >= 1
}

// --- kernel 5: output projection partials. grid (16 colblocks, KSPLIT2), 128 thr ---
__global__ __launch_bounds__(128) void out_partial_kernel(
    const float* __restrict__ ain, const float* __restrict__ wo,
    float* __restrict__ part) {
  int n = blockIdx.x * 128 + threadIdx.x;  // 0..2047
  int kz = blockIdx.y;
  int k0 = kz * KCH2;
  const float* Wp = wo + (size_t)k0 * HIDDEN + n;
  float acc[BATCH];
#pragma unroll
  for (int b = 0; b < BATCH; ++b) acc[b] = 0.f;
  float wa[8], wb[8];
#pragma unroll
  for (int j = 0; j < 8; ++j) wa[j] = Wp[(size_t)j * HIDDEN];
#pragma unroll
  for (int kk = 0; kk < KCH2; kk += 16) {
#pragma unroll
    for (int j = 0; j < 8; ++j) wb[j] = Wp[(size_t)(kk + 8 + j) * HIDDEN];
#pragma unroll
    for (int j = 0; j < 8; ++j) {
#pragma unroll
      for (int b = 0; b < BATCH; ++b)
        acc[b] = fmaf(ain[b * HIDDEN + k0 + kk + j], wa[j], acc[b]);  // uniform -> s_load
    }
    if (kk + 16 < KCH2) {
#pragma unroll
      for (int j = 0; j < 8; ++j) wa[j] = Wp[(size_t)(kk + 16 + j) * HIDDEN];
    }
#pragma unroll
    for (int j = 0; j < 8; ++j) {
#pragma unroll
      for (int b = 0; b < BATCH; ++b)
        acc[b] = fmaf(ain[b * HIDDEN + k0 + kk + 8 + j], wb[j], acc[b]);
    }
  }
#pragma unroll
  for (int b = 0; b < BATCH; ++b)
    part[(size_t)kz * (BATCH * HIDDEN) + b * HIDDEN + n] = acc[b];
}

// --- kernel 6: reduce + store f32 output. grid (256), 256 thr ---
__global__ __launch_bounds__(256) void out_finish_kernel(
    const float* __restrict__ part, float* __restrict__ outp) {
  int idx = blockIdx.x * 256 + threadIdx.x;  // 0..65535
  float v = 0.f;
#pragma unroll
  for (int z = 0; z < KSPLIT2; ++z)
    v += part[(size_t)z * (BATCH * HIDDEN) + idx];
  outp[idx] = v;
}

extern "C" void kernel_launch(void* const* d_in, const int* in_sizes, int n_in,
                              void* d_out, int out_size, void* d_ws, size_t ws_size,
                              hipStream_t stream) {
  const float* hidden = (const float*)d_in[0];
  const float* cosb   = (const float*)d_in[1];
  const float* sinb   = (const float*)d_in[2];
  const float* kc     = (const float*)d_in[3];
  const float* vc     = (const float*)d_in[4];
  const float* wq     = (const float*)d_in[5];
  const float* wk     = (const float*)d_in[6];
  const float* wv     = (const float*)d_in[7];
  const float* wo     = (const float*)d_in[8];
  const float* qnw    = (const float*)d_in[9];
  const float* knw    = (const float*)d_in[10];
  const int* btab     = (const int*)d_in[11];
  const int* clen     = (const int*)d_in[12];
  float* out = (float*)d_out;
  float* ws  = (float*)d_ws;

  float* qkvp = ws + WS_QKVP;
  float* qbuf = ws + WS_QBUF;
  float* aout = ws + WS_AOUT;
  float* pacc = ws + WS_PACC;
  float* pml  = ws + WS_PML;
  float* outp = ws + WS_OUTP;

  float* outO = out;             // [32,2048]
  float* outK = out + 65536;     // [32,8,128]
  float* outV = out + 98304;     // [32,8,128]

  hipLaunchKernelGGL(qkv_partial_kernel, dim3(32, KSPLIT1), dim3(128), 0, stream,
                     hidden, wq, wk, wv, qkvp);
  hipLaunchKernelGGL(qkv_finish_kernel, dim3(32, 32), dim3(128), 0, stream,
                     qkvp, cosb, sinb, qnw, knw, qbuf, outK, outV);
  hipLaunchKernelGGL(attn_kernel, dim3(BATCH, NUM_KV, CSPLIT), dim3(256), 0, stream,
                     qbuf, kc, vc, btab, clen, pacc, pml);
  hipLaunchKernelGGL(attn_combine_kernel, dim3(BATCH, NUM_KV), dim3(256), 0, stream,
                     pacc, pml, aout);
  hipLaunchKernelGGL(out_partial_kernel, dim3(16, KSPLIT2), dim3(128), 0, stream,
                     aout, wo, outp);
  hipLaunchKernelGGL(out_finish_kernel, dim3(256), dim3(256), 0, stream,
                     outp, outO);
}

// Round 2
// 584.092 us; speedup vs baseline: 1.0569x; 1.0099x over previous
//
#include <hip/hip_runtime.h>

#define HIDDEN 2048
#define HEAD_DIM 128
#define NUM_KV 8
#define BATCH 32
#define MAX_PAGES 128
#define PAGE 16
#define QKV_COLS 4096          // 2048 q | 1024 k | 1024 v
#define KSPLIT1 32
#define KCH1 (HIDDEN / KSPLIT1)   // 64
#define CSPLIT 8
#define KSPLIT2 64
#define KCH2 (HIDDEN / KSPLIT2)   // 32

// ws layout (float offsets). Regions reused across sequential phases.
#define WS_QKVP 0                 // 32*32*4096 = 4194304
#define WS_QBUF 4194304           // 65536 (q post norm+rope, f32)
#define WS_AOUT 4259840           // 65536 (attn output, f32)
#define WS_PACC 0                 // 32*8*8*256 = 524288 (reuses QKVP region)
#define WS_PML  524288            // 32*8*8*4 = 8192
#define WS_OUTP 0                 // 64*65536 = 4194304 (reuses again)
// high-water: 4325376 floats = 17.3 MB

// --- kernel 1: QKV projection partials. grid (32 colblocks, KSPLIT1), 128 thr ---
// 8-deep weight prefetch: 8 coalesced loads in flight during each 256-FMA stage.
__global__ __launch_bounds__(128) void qkv_partial_kernel(
    const float* __restrict__ x, const float* __restrict__ wq,
    const float* __restrict__ wk, const float* __restrict__ wv,
    float* __restrict__ part) {
  int n = blockIdx.x * 128 + threadIdx.x;   // 0..4095
  int kz = blockIdx.y;
  int k0 = kz * KCH1;
  const float* W; int ldw, col;             // block-uniform branch (128-col blocks)
  if (n < 2048)      { W = wq; ldw = 2048; col = n; }
  else if (n < 3072) { W = wk; ldw = 1024; col = n - 2048; }
  else               { W = wv; ldw = 1024; col = n - 3072; }
  const float* Wp = W + (size_t)k0 * ldw + col;
  float acc[BATCH];
#pragma unroll
  for (int b = 0; b < BATCH; ++b) acc[b] = 0.f;
  float wa[8], wb[8];
#pragma unroll
  for (int j = 0; j < 8; ++j) wa[j] = Wp[(size_t)j * ldw];
#pragma unroll
  for (int kk = 0; kk < KCH1; kk += 16) {
#pragma unroll
    for (int j = 0; j < 8; ++j) wb[j] = Wp[(size_t)(kk + 8 + j) * ldw];
#pragma unroll
    for (int j = 0; j < 8; ++j) {
#pragma unroll
      for (int b = 0; b < BATCH; ++b)
        acc[b] = fmaf(x[b * HIDDEN + k0 + kk + j], wa[j], acc[b]);  // x uniform -> s_load
    }
    if (kk + 16 < KCH1) {
#pragma unroll
      for (int j = 0; j < 8; ++j) wa[j] = Wp[(size_t)(kk + 16 + j) * ldw];
    }
#pragma unroll
    for (int j = 0; j < 8; ++j) {
#pragma unroll
      for (int b = 0; b < BATCH; ++b)
        acc[b] = fmaf(x[b * HIDDEN + k0 + kk + 8 + j], wb[j], acc[b]);
    }
  }
#pragma unroll
  for (int b = 0; b < BATCH; ++b)
    part[((size_t)kz * BATCH + b) * QKV_COLS + n] = acc[b];
}

// --- kernel 2: reduce partials, rmsnorm + rope, emit q(ws f32), k,v (d_out f32) ---
// grid (32 batch, 32 slots: 16 q heads, 8 k heads, 8 v heads), 128 thr
__global__ __launch_bounds__(128) void qkv_finish_kernel(
    const float* __restrict__ part, const float* __restrict__ cosb,
    const float* __restrict__ sinb, const float* __restrict__ qnw,
    const float* __restrict__ knw, float* __restrict__ qbuf,
    float* __restrict__ outk, float* __restrict__ outv) {
  int b = blockIdx.x;
  int s = blockIdx.y;
  int d = threadIdx.x;
  int col;
  if (s < 16)      col = s * 128 + d;
  else if (s < 24) col = 2048 + (s - 16) * 128 + d;
  else             col = 3072 + (s - 24) * 128 + d;
  float val = 0.f;
#pragma unroll
  for (int z = 0; z < KSPLIT1; ++z)
    val += part[((size_t)z * BATCH + b) * QKV_COLS + col];
  if (s >= 24) {  // v: raw projection, straight to output (block-uniform branch)
    outv[b * 1024 + (s - 24) * 128 + d] = val;
    return;
  }
  __shared__ float red[128];
  __shared__ float xs[128];
  red[d] = val * val;
  __syncthreads();
#pragma unroll
  for (int st = 64; st > 0; st >>= 1) {
    if (d < st) red[d] += red[d + st];
    __syncthreads();
  }
  float var = red[0] * (1.f / 128.f);
  float inv = rsqrtf(var + 1e-6f);
  const float* nw = (s < 16) ? qnw : knw;
  float xn = val * inv * nw[d];
  xs[d] = xn;
  __syncthreads();
  float c  = cosb[b * 128 + d];
  float sn = sinb[b * 128 + d];
  float rot = (d < 64) ? -xs[d + 64] : xs[d - 64];
  float o = xn * c + rot * sn;
  if (s < 16) qbuf[b * 2048 + s * 128 + d] = o;
  else        outk[b * 1024 + (s - 16) * 128 + d] = o;
}

// --- kernel 3: flash-decode attention, barrier-free main loop, BALANCED splits. ---
// grid (32, 8 kvh, 8 splits), 256 thr. Split sp owns pages [sp*npages/8,
// (sp+1)*npages/8) so all 8 splits are active for every batch (npages>=8):
// per-block work = npages/8 instead of fixed-16-or-0 -> no retired-block
// occupancy holes, kernel tail ~halves. Thread (pos,dp) keeps private
// online-softmax state; single LDS merge per split; K/V prefetched 1 page
// ahead (depth-2 would cross the 128-VGPR occupancy cliff).
__global__ __launch_bounds__(256) void attn_kernel(
    const float* __restrict__ qbuf, const float* __restrict__ kc,
    const float* __restrict__ vc, const int* __restrict__ btab,
    const int* __restrict__ clen, float* __restrict__ pacc,
    float* __restrict__ pml) {
  int b = blockIdx.x, g = blockIdx.y, sp = blockIdx.z;
  int tid = threadIdx.x;
  const float NEG_INF = -__builtin_huge_valf();
  int ctx = clen[b];
  int npages = (ctx + PAGE - 1) >> 4;
  int per = npages >> 3;                 // npages / CSPLIT
  int rem = npages & (CSPLIT - 1);
  int p0 = sp * per + min(sp, rem);
  int p1 = p0 + per + (sp < rem ? 1 : 0);

  int pos = tid >> 4, dp = tid & 15;
  float ql0[8], ql1[8];
  {
    const float4* q0 = (const float4*)(qbuf + b * 2048 + (g * 2 + 0) * 128 + dp * 8);
    const float4* q1 = (const float4*)(qbuf + b * 2048 + (g * 2 + 1) * 128 + dp * 8);
    float4 a = q0[0], c = q0[1];
    ql0[0]=a.x; ql0[1]=a.y; ql0[2]=a.z; ql0[3]=a.w;
    ql0[4]=c.x; ql0[5]=c.y; ql0[6]=c.z; ql0[7]=c.w;
    a = q1[0]; c = q1[1];
    ql1[0]=a.x; ql1[1]=a.y; ql1[2]=a.z; ql1[3]=a.w;
    ql1[4]=c.x; ql1[5]=c.y; ql1[6]=c.z; ql1[7]=c.w;
  }
  float acc0[8], acc1[8];
#pragma unroll
  for (int j = 0; j < 8; ++j) { acc0[j] = 0.f; acc1[j] = 0.f; }
  float m0 = NEG_INF, m1 = NEG_INF, l0 = 0.f, l1 = 0.f;
  const float scale = 0.08838834764831845f;

  float4 ck0, ck1, cv0, cv1;
  if (p0 < p1) {
    int page = btab[b * MAX_PAGES + p0];
    size_t base = ((size_t)(page * PAGE + pos) * NUM_KV + g) * HEAD_DIM + dp * 8;
    const float4* kp = (const float4*)(kc + base);
    const float4* vp = (const float4*)(vc + base);
    ck0 = kp[0]; ck1 = kp[1]; cv0 = vp[0]; cv1 = vp[1];
  }
  for (int p = p0; p < p1; ++p) {
    float4 nk0, nk1, nv0, nv1;
    if (p + 1 < p1) {              // prefetch next page (block-uniform branch)
      int page = btab[b * MAX_PAGES + p + 1];
      size_t base = ((size_t)(page * PAGE + pos) * NUM_KV + g) * HEAD_DIM + dp * 8;
      const float4* kp = (const float4*)(kc + base);
      const float4* vp = (const float4*)(vc + base);
      nk0 = kp[0]; nk1 = kp[1]; nv0 = vp[0]; nv1 = vp[1];
    }
    float s0 = 0.f, s1 = 0.f;
    s0 = fmaf(ck0.x, ql0[0], s0); s1 = fmaf(ck0.x, ql1[0], s1);
    s0 = fmaf(ck0.y, ql0[1], s0); s1 = fmaf(ck0.y, ql1[1], s1);
    s0 = fmaf(ck0.z, ql0[2], s0); s1 = fmaf(ck0.z, ql1[2], s1);
    s0 = fmaf(ck0.w, ql0[3], s0); s1 = fmaf(ck0.w, ql1[3], s1);
    s0 = fmaf(ck1.x, ql0[4], s0); s1 = fmaf(ck1.x, ql1[4], s1);
    s0 = fmaf(ck1.y, ql0[5], s0); s1 = fmaf(ck1.y, ql1[5], s1);
    s0 = fmaf(ck1.z, ql0[6], s0); s1 = fmaf(ck1.z, ql1[6], s1);
    s0 = fmaf(ck1.w, ql0[7], s0); s1 = fmaf(ck1.w, ql1[7], s1);
#pragma unroll
    for (int off = 1; off < 16; off <<= 1) {
      s0 += __shfl_xor(s0, off);
      s1 += __shfl_xor(s1, off);
    }
    bool valid = (p * PAGE + pos) < ctx;
    if (valid) {
      float t0 = s0 * scale;
      float mn = fmaxf(m0, t0);
      float a  = __expf(m0 - mn);      // m0=-inf first time -> 0
      float w  = __expf(t0 - mn);
      l0 = fmaf(l0, a, w); m0 = mn;
      acc0[0] = fmaf(acc0[0], a, w * cv0.x);
      acc0[1] = fmaf(acc0[1], a, w * cv0.y);
      acc0[2] = fmaf(acc0[2], a, w * cv0.z);
      acc0[3] = fmaf(acc0[3], a, w * cv0.w);
      acc0[4] = fmaf(acc0[4], a, w * cv1.x);
      acc0[5] = fmaf(acc0[5], a, w * cv1.y);
      acc0[6] = fmaf(acc0[6], a, w * cv1.z);
      acc0[7] = fmaf(acc0[7], a, w * cv1.w);
      float t1 = s1 * scale;
      float mn1 = fmaxf(m1, t1);
      float a1  = __expf(m1 - mn1);
      float w1  = __expf(t1 - mn1);
      l1 = fmaf(l1, a1, w1); m1 = mn1;
      acc1[0] = fmaf(acc1[0], a1, w1 * cv0.x);
      acc1[1] = fmaf(acc1[1], a1, w1 * cv0.y);
      acc1[2] = fmaf(acc1[2], a1, w1 * cv0.z);
      acc1[3] = fmaf(acc1[3], a1, w1 * cv0.w);
      acc1[4] = fmaf(acc1[4], a1, w1 * cv1.x);
      acc1[5] = fmaf(acc1[5], a1, w1 * cv1.y);
      acc1[6] = fmaf(acc1[6], a1, w1 * cv1.z);
      acc1[7] = fmaf(acc1[7], a1, w1 * cv1.w);
    }
    ck0 = nk0; ck1 = nk1; cv0 = nv0; cv1 = nv1;
  }

  // --- once-per-split merge across the 16 pos groups ---
  __shared__ float m_s[2][16], l_s[2][16];
  __shared__ float acc_s[2][16][128];
  if (dp == 0) {   // m,l identical across the 16-lane group (post-shfl)
    m_s[0][pos] = m0; m_s[1][pos] = m1;
    l_s[0][pos] = l0; l_s[1][pos] = l1;
  }
  *(float4*)&acc_s[0][pos][dp * 8]     = make_float4(acc0[0], acc0[1], acc0[2], acc0[3]);
  *(float4*)&acc_s[0][pos][dp * 8 + 4] = make_float4(acc0[4], acc0[5], acc0[6], acc0[7]);
  *(float4*)&acc_s[1][pos][dp * 8]     = make_float4(acc1[0], acc1[1], acc1[2], acc1[3]);
  *(float4*)&acc_s[1][pos][dp * 8 + 4] = make_float4(acc1[4], acc1[5], acc1[6], acc1[7]);
  __syncthreads();
  int r2 = tid >> 7, d2 = tid & 127;
  float M = NEG_INF;
#pragma unroll
  for (int q = 0; q < 16; ++q) M = fmaxf(M, m_s[r2][q]);
  float accT = 0.f, lT = 0.f;
  if (M != NEG_INF) {              // empty split -> zeros, M=-inf (combine handles)
#pragma unroll
    for (int q = 0; q < 16; ++q) {
      float w = __expf(m_s[r2][q] - M);   // m_s=-inf -> w=0
      accT = fmaf(w, acc_s[r2][q][d2], accT);
      lT   = fmaf(w, l_s[r2][q], lT);
    }
  }
  size_t pidx = ((size_t)b * NUM_KV + g) * CSPLIT + sp;
  pacc[pidx * 256 + tid] = accT;
  if (d2 == 0) {
    pml[pidx * 4 + r2 * 2 + 0] = M;
    pml[pidx * 4 + r2 * 2 + 1] = lT;
  }
}

// --- kernel 4: merge splits. grid (32, 8), 256 thr ---
__global__ __launch_bounds__(256) void attn_combine_kernel(
    const float* __restrict__ pacc, const float* __restrict__ pml,
    float* __restrict__ attn_out) {
  int b = blockIdx.x, g = blockIdx.y, tid = threadIdx.x;
  int r = tid >> 7, d = tid & 127;
  size_t base = ((size_t)b * NUM_KV + g) * CSPLIT;
  float M = -__builtin_huge_valf();
#pragma unroll
  for (int s = 0; s < CSPLIT; ++s)
    M = fmaxf(M, pml[(base + s) * 4 + r * 2]);
  float accT = 0.f, lT = 0.f;
#pragma unroll
  for (int s = 0; s < CSPLIT; ++s) {
    float ms = pml[(base + s) * 4 + r * 2];
    float ls = pml[(base + s) * 4 + r * 2 + 1];
    float w = __expf(ms - M);          // empty split: exp(-inf)=0
    accT = fmaf(w, pacc[(base + s) * 256 + tid], accT);
    lT = fmaf(w, ls, lT);
  }
  attn_out[b * 2048 + (g * 2 + r) * 128 + d] = accT / lT;   // lT >= 1
}

// --- kernel 5: output projection partials. grid (16 colblocks, KSPLIT2), 128 thr ---
// KSPLIT2=64 -> 1024 blocks = 2 waves/SIMD (was 1): latency exposure halved.
__global__ __launch_bounds__(128) void out_partial_kernel(
    const float* __restrict__ ain, const float* __restrict__ wo,
    float* __restrict__ part) {
  int n = blockIdx.x * 128 + threadIdx.x;  // 0..2047
  int kz = blockIdx.y;
  int k0 = kz * KCH2;
  const float* Wp = wo + (size_t)k0 * HIDDEN + n;
  float acc[BATCH];
#pragma unroll
  for (int b = 0; b < BATCH; ++b) acc[b] = 0.f;
  float wa[8], wb[8];
#pragma unroll
  for (int j = 0; j < 8; ++j) wa[j] = Wp[(size_t)j * HIDDEN];
#pragma unroll
  for (int kk = 0; kk < KCH2; kk += 16) {
#pragma unroll
    for (int j = 0; j < 8; ++j) wb[j] = Wp[(size_t)(kk + 8 + j) * HIDDEN];
#pragma unroll
    for (int j = 0; j < 8; ++j) {
#pragma unroll
      for (int b = 0; b < BATCH; ++b)
        acc[b] = fmaf(ain[b * HIDDEN + k0 + kk + j], wa[j], acc[b]);  // uniform -> s_load
    }
    if (kk + 16 < KCH2) {
#pragma unroll
      for (int j = 0; j < 8; ++j) wa[j] = Wp[(size_t)(kk + 16 + j) * HIDDEN];
    }
#pragma unroll
    for (int j = 0; j < 8; ++j) {
#pragma unroll
      for (int b = 0; b < BATCH; ++b)
        acc[b] = fmaf(ain[b * HIDDEN + k0 + kk + 8 + j], wb[j], acc[b]);
    }
  }
#pragma unroll
  for (int b = 0; b < BATCH; ++b)
    part[(size_t)kz * (BATCH * HIDDEN) + b * HIDDEN + n] = acc[b];
}

// --- kernel 6: reduce + store f32 output. grid (256), 256 thr ---
__global__ __launch_bounds__(256) void out_finish_kernel(
    const float* __restrict__ part, float* __restrict__ outp) {
  int idx = blockIdx.x * 256 + threadIdx.x;  // 0..65535
  float v = 0.f;
#pragma unroll
  for (int z = 0; z < KSPLIT2; ++z)
    v += part[(size_t)z * (BATCH * HIDDEN) + idx];
  outp[idx] = v;
}

extern "C" void kernel_launch(void* const* d_in, const int* in_sizes, int n_in,
                              void* d_out, int out_size, void* d_ws, size_t ws_size,
                              hipStream_t stream) {
  const float* hidden = (const float*)d_in[0];
  const float* cosb   = (const float*)d_in[1];
  const float* sinb   = (const float*)d_in[2];
  const float* kc     = (const float*)d_in[3];
  const float* vc     = (const float*)d_in[4];
  const float* wq     = (const float*)d_in[5];
  const float* wk     = (const float*)d_in[6];
  const float* wv     = (const float*)d_in[7];
  const float* wo     = (const float*)d_in[8];
  const float* qnw    = (const float*)d_in[9];
  const float* knw    = (const float*)d_in[10];
  const int* btab     = (const int*)d_in[11];
  const int* clen     = (const int*)d_in[12];
  float* out = (float*)d_out;
  float* ws  = (float*)d_ws;

  float* qkvp = ws + WS_QKVP;
  float* qbuf = ws + WS_QBUF;
  float* aout = ws + WS_AOUT;
  float* pacc = ws + WS_PACC;
  float* pml  = ws + WS_PML;
  float* outp = ws + WS_OUTP;

  float* outO = out;             // [32,2048]
  float* outK = out + 65536;     // [32,8,128]
  float* outV = out + 98304;     // [32,8,128]

  hipLaunchKernelGGL(qkv_partial_kernel, dim3(32, KSPLIT1), dim3(128), 0, stream,
                     hidden, wq, wk, wv, qkvp);
  hipLaunchKernelGGL(qkv_finish_kernel, dim3(32, 32), dim3(128), 0, stream,
                     qkvp, cosb, sinb, qnw, knw, qbuf, outK, outV);
  hipLaunchKernelGGL(attn_kernel, dim3(BATCH, NUM_KV, CSPLIT), dim3(256), 0, stream,
                     qbuf, kc, vc, btab, clen, pacc, pml);
  hipLaunchKernelGGL(attn_combine_kernel, dim3(BATCH, NUM_KV), dim3(256), 0, stream,
                     pacc, pml, aout);
  hipLaunchKernelGGL(out_partial_kernel, dim3(16, KSPLIT2), dim3(128), 0, stream,
                     aout, wo, outp);
  hipLaunchKernelGGL(out_finish_kernel, dim3(256), dim3(256), 0, stream,
                     outp, outO);
}